// Round 4
// baseline (104.689 us; speedup 1.0000x reference)
//
#include <hip/hip_runtime.h>
#include <hip/hip_fp16.h>

#define T_CTX 100
#define C_DIM 384
#define H_DIM 64

typedef _Float16 half8   __attribute__((ext_vector_type(8)));
typedef _Float16 half2_t __attribute__((ext_vector_type(2)));
typedef float    f32x4   __attribute__((ext_vector_type(4)));

// ---- LDS layout, units = halfs (2B) ----
// Persistent (phase2/3):
//   QH [8 qtile][2 kk][64 lane][8] @ 0      (8192 halfs)
//   QL                             @ 8192   (8192)
//   KH [7 keytile][2 kk][64][8]    @ 16384  (7168)
//   KL                             @ 23552  (7168)
//   VT [4 jh][4 kk][64][8]         @ 30720  (8192)
//   total = 38912 halfs = 77824 B -> 2 blocks/CU
// Overlay: PS [8 wid][4 kk][64][8] @ 0 (16384 halfs), written after q/k dead.
#define QH_OFF 0
#define QL_OFF 8192
#define KH_OFF 16384
#define KL_OFF 23552
#define VT_OFF 30720
#define PS_OFF 0
#define SMEM_BYTES 77824

__global__ void prep_w_kernel(const float* __restrict__ Wq,
                              const float* __restrict__ Wk,
                              const float* __restrict__ Wv,
                              _Float16* __restrict__ wf_hi,
                              _Float16* __restrict__ wf_lo) {
    int idx = blockIdx.x * 256 + threadIdx.x;   // over 12*12*64 = 9216 frag-lanes
    if (idx >= 9216) return;
    int lane  = idx & 63;
    int chunk = (idx >> 6) % 12;
    int jt    = idx / (64 * 12);
    int col   = jt * 16 + (lane & 15);          // global N col 0..191 (q|k|v)
    const float* W = (col < 64) ? Wq : ((col < 128) ? Wk : Wv);
    int h = col & 63;
    int cbase = chunk * 32 + (lane >> 4) * 8;   // K index base
    #pragma unroll
    for (int e = 0; e < 8; ++e) {
        float f = W[(size_t)(cbase + e) * H_DIM + h];
        _Float16 hi = (_Float16)f;
        _Float16 lo = (_Float16)(f - (float)hi);
        size_t o = (size_t)idx * 8 + e;
        wf_hi[o] = hi;
        wf_lo[o] = lo;
    }
}

// f32x8 (as two f32x4) -> fp16 hi/lo half8 planes
__device__ inline void cvt_hilo(f32x4 a, f32x4 c, half8& hh, half8& ll) {
    float f[8] = {a[0], a[1], a[2], a[3], c[0], c[1], c[2], c[3]};
    #pragma unroll
    for (int u = 0; u < 8; ++u) {
        _Float16 h = (_Float16)f[u];
        hh[u] = h;
        ll[u] = (_Float16)(f[u] - (float)h);
    }
}

__global__ __launch_bounds__(512, 4)
void head_kernel(const float* __restrict__ x,
                 const _Float16* __restrict__ wf_hi,
                 const _Float16* __restrict__ wf_lo,
                 float* __restrict__ out) {
    extern __shared__ _Float16 sm[];

    const int b    = blockIdx.x;
    const int tid  = threadIdx.x;
    const int lane = tid & 63;
    const int wid  = tid >> 6;      // 8 waves
    const int l15  = lane & 15;
    const int lg   = lane >> 4;     // 0..3
    const int mh   = wid >> 2;      // phase1: row half (rows mh*64..)
    const int nw   = wid & 3;

    // balanced tile assignment: each wave: 2 q/k col-tiles (3 products) + 1 v tile (1 product)
    const int tl0 = nw * 2;         // col-tiles 0..7 = q(0-3), k(4-7)
    const int tl1 = nw * 2 + 1;
    const int tlv = 8 + nw;         // v tiles 8..11
    const int NI  = (mh == 0) ? 4 : 3;   // mh=1 skips rows 112..127 (all masked)

    const float* xb = x + (size_t)b * T_CTX * C_DIM;

    // ================= phase 1: q,k,v = x @ W — no LDS, no barriers =================
    f32x4 acc0[4], acc1[4], accv[4];
    #pragma unroll
    for (int i = 0; i < 4; ++i) {
        acc0[i] = (f32x4){0.f,0.f,0.f,0.f};
        acc1[i] = (f32x4){0.f,0.f,0.f,0.f};
        accv[i] = (f32x4){0.f,0.f,0.f,0.f};
    }

    #pragma unroll 1
    for (int kc = 0; kc < 12; ++kc) {
        // W fragments for this chunk (L2-resident)
        const size_t wo0 = ((size_t)(tl0 * 12 + kc) * 64 + lane) * 8;
        const size_t wo1 = ((size_t)(tl1 * 12 + kc) * 64 + lane) * 8;
        const size_t wov = ((size_t)(tlv * 12 + kc) * 64 + lane) * 8;
        half8 b0h = *(const half8*)(wf_hi + wo0);
        half8 b0l = *(const half8*)(wf_lo + wo0);
        half8 b1h = *(const half8*)(wf_hi + wo1);
        half8 b1l = *(const half8*)(wf_lo + wo1);
        half8 bvh = *(const half8*)(wf_hi + wov);

        // x A-fragments: global -> reg -> fp16 hi/lo
        half8 ah[4], al[4];
        #pragma unroll
        for (int i = 0; i < 4; ++i) {
            if (i >= NI) break;
            int row = mh * 64 + i * 16 + l15;
            f32x4 xa = (f32x4){0.f,0.f,0.f,0.f};
            f32x4 xc = (f32x4){0.f,0.f,0.f,0.f};
            if (row < T_CTX) {
                const float* p = xb + (size_t)row * C_DIM + kc * 32 + lg * 8;
                xa = *(const f32x4*)p;
                xc = *(const f32x4*)(p + 4);
            }
            cvt_hilo(xa, xc, ah[i], al[i]);
        }

        #pragma unroll
        for (int i = 0; i < 4; ++i) {
            if (i >= NI) break;
            acc0[i] = __builtin_amdgcn_mfma_f32_16x16x32_f16(ah[i], b0h, acc0[i], 0, 0, 0);
            acc0[i] = __builtin_amdgcn_mfma_f32_16x16x32_f16(al[i], b0h, acc0[i], 0, 0, 0);
            acc0[i] = __builtin_amdgcn_mfma_f32_16x16x32_f16(ah[i], b0l, acc0[i], 0, 0, 0);
            acc1[i] = __builtin_amdgcn_mfma_f32_16x16x32_f16(ah[i], b1h, acc1[i], 0, 0, 0);
            acc1[i] = __builtin_amdgcn_mfma_f32_16x16x32_f16(al[i], b1h, acc1[i], 0, 0, 0);
            acc1[i] = __builtin_amdgcn_mfma_f32_16x16x32_f16(ah[i], b1l, acc1[i], 0, 0, 0);
            accv[i] = __builtin_amdgcn_mfma_f32_16x16x32_f16(ah[i], bvh, accv[i], 0, 0, 0);
        }
    }

    // VT zero-fill rows 112..127 (skipped tiles) — region [jh*2048+1792, +256)
    {
        int jh = tid >> 7;
        int w2 = (tid & 127) * 2;
        *(half2_t*)(sm + VT_OFF + jh * 2048 + 1792 + w2) = (half2_t){(_Float16)0.f, (_Float16)0.f};
    }

    // epilogue: scatter acc -> fragment-packed LDS
    #pragma unroll
    for (int tsel = 0; tsel < 3; ++tsel) {
        const int tl = (tsel == 0) ? tl0 : (tsel == 1) ? tl1 : tlv;
        f32x4* at = (tsel == 0) ? acc0 : (tsel == 1) ? acc1 : accv;
        const int ncol = tl * 16 + l15;
        #pragma unroll
        for (int i = 0; i < 4; ++i) {
            if (i >= NI) break;
            #pragma unroll
            for (int r = 0; r < 4; ++r) {
                int row = mh * 64 + i * 16 + lg * 4 + r;   // time index
                float val = at[i][r];
                if (tl < 4) {            // q[t][h=ncol]
                    int off = (row >> 4) * 1024 + (ncol >> 5) * 512
                            + (((ncol >> 3) & 3) * 16 + (row & 15)) * 8 + (ncol & 7);
                    _Float16 h = (_Float16)val;
                    sm[QH_OFF + off] = h;
                    sm[QL_OFF + off] = (_Float16)(val - (float)h);
                } else if (tl < 8) {     // k[t][h]
                    if (row < 112) {
                        int hc = ncol - 64;
                        int off = (row >> 4) * 1024 + (hc >> 5) * 512
                                + (((hc >> 3) & 3) * 16 + (row & 15)) * 8 + (hc & 7);
                        _Float16 h = (_Float16)val;
                        sm[KH_OFF + off] = h;
                        sm[KL_OFF + off] = (_Float16)(val - (float)h);
                    }
                } else {                 // v[t][h]
                    int hc = ncol - 128;
                    int off = (hc >> 4) * 2048 + (row >> 5) * 512
                            + (((row >> 3) & 3) * 16 + (hc & 15)) * 8 + (row & 7);
                    sm[VT_OFF + off] = (_Float16)val;
                }
            }
        }
    }
    __syncthreads();

    // ================= phase 2: scores (split fp16), softmax ==========================
    f32x4 sacc[7];
    #pragma unroll
    for (int j = 0; j < 7; ++j) sacc[j] = (f32x4){0.f,0.f,0.f,0.f};

    #pragma unroll
    for (int kk = 0; kk < 2; ++kk) {
        half8 qh = *(const half8*)(sm + QH_OFF + wid * 1024 + kk * 512 + lane * 8);
        half8 ql = *(const half8*)(sm + QL_OFF + wid * 1024 + kk * 512 + lane * 8);
        #pragma unroll
        for (int j = 0; j < 7; ++j) {
            half8 kh = *(const half8*)(sm + KH_OFF + j * 1024 + kk * 512 + lane * 8);
            half8 kl = *(const half8*)(sm + KL_OFF + j * 1024 + kk * 512 + lane * 8);
            sacc[j] = __builtin_amdgcn_mfma_f32_16x16x32_f16(qh, kh, sacc[j], 0, 0, 0);
            sacc[j] = __builtin_amdgcn_mfma_f32_16x16x32_f16(ql, kh, sacc[j], 0, 0, 0);
            sacc[j] = __builtin_amdgcn_mfma_f32_16x16x32_f16(qh, kl, sacc[j], 0, 0, 0);
        }
    }

    float rmax[4] = {-1e30f, -1e30f, -1e30f, -1e30f};
    float sv[7][4];
    #pragma unroll
    for (int j = 0; j < 7; ++j) {
        int key = j * 16 + l15;
        #pragma unroll
        for (int r = 0; r < 4; ++r) {
            int row = wid * 16 + lg * 4 + r;
            // faithful bug: multiply by sqrt(64)=8; causal + key<100 mask
            float s = (key <= row && key < T_CTX) ? sacc[j][r] * 8.0f : -1e30f;
            sv[j][r] = s;
            rmax[r] = fmaxf(rmax[r], s);
        }
    }
    #pragma unroll
    for (int r = 0; r < 4; ++r) {
        #pragma unroll
        for (int d = 1; d < 16; d <<= 1)
            rmax[r] = fmaxf(rmax[r], __shfl_xor(rmax[r], d, 64));
    }

    __syncthreads();   // all waves done reading q/k before PS overlays that region

    float rsum[4] = {0.f, 0.f, 0.f, 0.f};
    #pragma unroll
    for (int j = 0; j < 7; ++j) {
        int key = j * 16 + l15;
        #pragma unroll
        for (int r = 0; r < 4; ++r) {
            float p = __expf(sv[j][r] - rmax[r]);   // masked -> 0
            rsum[r] += p;
            int a = lg * 4 + r;
            int off = wid * 2048 + (key >> 5) * 512
                    + (((key >> 3) & 3) * 16 + a) * 8 + (key & 7);
            sm[PS_OFF + off] = (_Float16)p;
        }
    }
    #pragma unroll
    for (int r = 0; r < 4; ++r) {                   // zero pad keys 112..127
        int key = 112 + l15;
        int a = lg * 4 + r;
        int off = wid * 2048 + (key >> 5) * 512
                + (((key >> 3) & 3) * 16 + a) * 8 + (key & 7);
        sm[PS_OFF + off] = (_Float16)0.f;
        #pragma unroll
        for (int d = 1; d < 16; d <<= 1)
            rsum[r] += __shfl_xor(rsum[r], d, 64);
    }
    __syncthreads();

    // ================= phase 3: out = (P @ V) / rowsum ================================
    f32x4 oacc[4];
    #pragma unroll
    for (int j = 0; j < 4; ++j) oacc[j] = (f32x4){0.f,0.f,0.f,0.f};
    #pragma unroll
    for (int kk = 0; kk < 4; ++kk) {
        half8 pa = *(const half8*)(sm + PS_OFF + wid * 2048 + kk * 512 + lane * 8);
        #pragma unroll
        for (int jh = 0; jh < 4; ++jh) {
            half8 vb = *(const half8*)(sm + VT_OFF + jh * 2048 + kk * 512 + lane * 8);
            oacc[jh] = __builtin_amdgcn_mfma_f32_16x16x32_f16(pa, vb, oacc[jh], 0, 0, 0);
        }
    }
    float rinv[4];
    #pragma unroll
    for (int r = 0; r < 4; ++r) rinv[r] = 1.0f / rsum[r];
    #pragma unroll
    for (int jh = 0; jh < 4; ++jh) {
        #pragma unroll
        for (int r = 0; r < 4; ++r) {
            int t = wid * 16 + lg * 4 + r;
            if (t < T_CTX)
                out[((size_t)b * T_CTX + t) * H_DIM + jh * 16 + l15] = oacc[jh][r] * rinv[r];
        }
    }
}

extern "C" void kernel_launch(void* const* d_in, const int* in_sizes, int n_in,
                              void* d_out, int out_size, void* d_ws, size_t ws_size,
                              hipStream_t stream) {
    const float* x  = (const float*)d_in[0];
    const float* Wq = (const float*)d_in[1];
    const float* Wk = (const float*)d_in[2];
    const float* Wv = (const float*)d_in[3];

    _Float16* wf_hi = (_Float16*)d_ws;                 // 12*12*64*8 halfs = 147456 B
    _Float16* wf_lo = wf_hi + (size_t)9216 * 8;        // total ws use: 294912 B

    prep_w_kernel<<<36, 256, 0, stream>>>(Wq, Wk, Wv, wf_hi, wf_lo);

    (void)hipFuncSetAttribute((const void*)head_kernel,
                              hipFuncAttributeMaxDynamicSharedMemorySize, SMEM_BYTES);
    head_kernel<<<1024, 512, SMEM_BYTES, stream>>>(x, wf_hi, wf_lo, (float*)d_out);
}

// Round 5
// 75.178 us; speedup vs baseline: 1.3926x; 1.3926x over previous
//
#include <hip/hip_runtime.h>
#include <hip/hip_fp16.h>

#define T_CTX 100
#define C_DIM 384
#define H_DIM 64

typedef _Float16 half8   __attribute__((ext_vector_type(8)));
typedef _Float16 half2_t __attribute__((ext_vector_type(2)));
typedef float    f32x4   __attribute__((ext_vector_type(4)));

// ---- LDS layout, units = halfs (2B) ----
// Persistent (phase2/3), 7 row-tiles (rows 0..111):
//   QH [7][2 kk][64][8] @ 0      (7168 halfs)
//   QL                  @ 7168   (7168)
//   KH [7][2 kk][64][8] @ 14336  (7168)
//   KL                  @ 21504  (7168)
//   VT [4 jh][4 kk][64][8] @ 28672 (8192)
//   total 36864 halfs = 73728 B -> 2 blocks/CU
// Overlays @0 (dead regions at time of use):
//   XS: fp32 x-staging, 2 buf x [128][36] floats (9216 f32 = 36864 B)
//   PS: [7 wid][4 kk][64][8] halfs (14336 = exactly QH+QL)
#define QH_OFF 0
#define QL_OFF 7168
#define KH_OFF 14336
#define KL_OFF 21504
#define VT_OFF 28672
#define PS_OFF 0
#define SMEM_BYTES 73728
#define XS_STRIDE_F 36
#define XS_BUF_F 4608

__global__ void prep_w_kernel(const float* __restrict__ Wq,
                              const float* __restrict__ Wk,
                              const float* __restrict__ Wv,
                              _Float16* __restrict__ wf_hi,
                              _Float16* __restrict__ wf_lo) {
    int idx = blockIdx.x * 256 + threadIdx.x;   // over 12*12*64 = 9216 frag-lanes
    if (idx >= 9216) return;
    int lane  = idx & 63;
    int chunk = (idx >> 6) % 12;
    int jt    = idx / (64 * 12);
    int col   = jt * 16 + (lane & 15);          // global N col 0..191 (q|k|v)
    const float* W = (col < 64) ? Wq : ((col < 128) ? Wk : Wv);
    int h = col & 63;
    int cbase = chunk * 32 + (lane >> 4) * 8;   // K index base
    #pragma unroll
    for (int e = 0; e < 8; ++e) {
        float f = W[(size_t)(cbase + e) * H_DIM + h];
        _Float16 hi = (_Float16)f;
        _Float16 lo = (_Float16)(f - (float)hi);
        size_t o = (size_t)idx * 8 + e;
        wf_hi[o] = hi;
        wf_lo[o] = lo;
    }
}

// 8 fp32 (two f32x4) -> fp16 hi/lo half8 planes (scalar casts; compiler emits v_cvt)
__device__ inline void cvt_hilo(f32x4 a, f32x4 c, half8& hh, half8& ll) {
    float f[8] = {a[0], a[1], a[2], a[3], c[0], c[1], c[2], c[3]};
    #pragma unroll
    for (int u = 0; u < 8; ++u) {
        _Float16 h = (_Float16)f[u];
        hh[u] = h;
        ll[u] = (_Float16)(f[u] - (float)h);
    }
}

__global__ __launch_bounds__(512, 4)
void head_kernel(const float* __restrict__ x,
                 const _Float16* __restrict__ wf_hi,
                 const _Float16* __restrict__ wf_lo,
                 float* __restrict__ out) {
    extern __shared__ _Float16 sm[];
    float* xsf = (float*)sm;

    const int b    = blockIdx.x;
    const int tid  = threadIdx.x;
    const int lane = tid & 63;
    const int wid  = tid >> 6;      // 8 waves
    const int l15  = lane & 15;
    const int lg   = lane >> 4;     // 0..3
    const int mh   = wid >> 2;      // row half
    const int nw   = wid & 3;
    const int NI   = (mh == 0) ? 4 : 3;   // mh=1 skips rows 112..127
    const bool isK = (nw >= 2);

    // wave -> B tiles (wf layout: tiles 0-3 q, 4-7 k, 8-11 v)
    int t0, t1, t2, t3;
    if (!isK) { t0 = nw * 2; t1 = t0 + 1; t2 = 8 + nw * 2; t3 = t2 + 1; }  // 2q + 2v
    else      { t0 = 4 + (nw - 2) * 2; t1 = t0 + 1; t2 = t0; t3 = t1; }    // 2k (hi+lo)

    const float* xb = x + (size_t)b * T_CTX * C_DIM;

    // staging slots: thread covers rows r0 (0..63) and r1 (64..127), 16B granule c4
    const int r0 = tid >> 3, r1 = r0 + 64, c4 = tid & 7;

    // ================= phase 1: q,k,v = x @ W (fp32-staged LDS, dbuf) =================
    f32x4 acc0[4], acc1[4], acc2[4], acc3[4];
    #pragma unroll
    for (int i = 0; i < 4; ++i) {
        acc0[i] = (f32x4){0.f,0.f,0.f,0.f};
        acc1[i] = (f32x4){0.f,0.f,0.f,0.f};
        acc2[i] = (f32x4){0.f,0.f,0.f,0.f};
        acc3[i] = (f32x4){0.f,0.f,0.f,0.f};
    }

    {   // prologue: stage chunk 0 -> buf 0
        f32x4 va = (r0 < T_CTX) ? *(const f32x4*)(xb + (size_t)r0 * C_DIM + c4 * 4)
                                : (f32x4){0.f,0.f,0.f,0.f};
        f32x4 vb = (r1 < T_CTX) ? *(const f32x4*)(xb + (size_t)r1 * C_DIM + c4 * 4)
                                : (f32x4){0.f,0.f,0.f,0.f};
        *(f32x4*)(xsf + r0 * XS_STRIDE_F + c4 * 4) = va;
        *(f32x4*)(xsf + r1 * XS_STRIDE_F + c4 * 4) = vb;
    }
    __syncthreads();

    #pragma unroll 1
    for (int kc = 0; kc < 12; ++kc) {
        const int nk = kc + 1;
        f32x4 lda = (f32x4){0.f,0.f,0.f,0.f}, ldb = (f32x4){0.f,0.f,0.f,0.f};
        if (nk < 12) {   // issue next-chunk global loads early
            if (r0 < T_CTX) lda = *(const f32x4*)(xb + (size_t)r0 * C_DIM + nk * 32 + c4 * 4);
            if (r1 < T_CTX) ldb = *(const f32x4*)(xb + (size_t)r1 * C_DIM + nk * 32 + c4 * 4);
        }
        const float* xc = xsf + (kc & 1) * XS_BUF_F;

        const size_t wo0 = ((size_t)(t0 * 12 + kc) * 64 + lane) * 8;
        const size_t wo1 = ((size_t)(t1 * 12 + kc) * 64 + lane) * 8;
        half8 B0 = *(const half8*)(wf_hi + wo0);
        half8 B1 = *(const half8*)(wf_hi + wo1);
        half8 B2, B3;
        if (!isK) {
            B2 = *(const half8*)(wf_hi + ((size_t)(t2 * 12 + kc) * 64 + lane) * 8);
            B3 = *(const half8*)(wf_hi + ((size_t)(t3 * 12 + kc) * 64 + lane) * 8);
        } else {
            B2 = *(const half8*)(wf_lo + wo0);
            B3 = *(const half8*)(wf_lo + wo1);
        }

        #pragma unroll
        for (int i = 0; i < 4; ++i) {
            if (i >= NI) break;
            int row = mh * 64 + i * 16 + l15;
            const float* p = xc + row * XS_STRIDE_F + lg * 8;
            f32x4 xa = *(const f32x4*)p;
            f32x4 xv = *(const f32x4*)(p + 4);
            half8 ah, al;
            cvt_hilo(xa, xv, ah, al);
            // q (2-prod) / k (3-prod) on acc0/acc1; v (1-prod) on acc2/acc3
            acc0[i] = __builtin_amdgcn_mfma_f32_16x16x32_f16(ah, B0, acc0[i], 0, 0, 0);
            acc0[i] = __builtin_amdgcn_mfma_f32_16x16x32_f16(al, B0, acc0[i], 0, 0, 0);
            acc1[i] = __builtin_amdgcn_mfma_f32_16x16x32_f16(ah, B1, acc1[i], 0, 0, 0);
            acc1[i] = __builtin_amdgcn_mfma_f32_16x16x32_f16(al, B1, acc1[i], 0, 0, 0);
            if (!isK) {
                acc2[i] = __builtin_amdgcn_mfma_f32_16x16x32_f16(ah, B2, acc2[i], 0, 0, 0);
                acc3[i] = __builtin_amdgcn_mfma_f32_16x16x32_f16(ah, B3, acc3[i], 0, 0, 0);
            } else {
                acc0[i] = __builtin_amdgcn_mfma_f32_16x16x32_f16(ah, B2, acc0[i], 0, 0, 0);
                acc1[i] = __builtin_amdgcn_mfma_f32_16x16x32_f16(ah, B3, acc1[i], 0, 0, 0);
            }
        }

        if (nk < 12) {   // write next chunk into the other buffer
            float* xn = xsf + (nk & 1) * XS_BUF_F;
            *(f32x4*)(xn + r0 * XS_STRIDE_F + c4 * 4) = lda;
            *(f32x4*)(xn + r1 * XS_STRIDE_F + c4 * 4) = ldb;
        }
        __syncthreads();
    }

    // VT zero-fill rows 112..127 (kk=3, lanes 32..63)
    {
        int jh = tid >> 7;
        int w2 = (tid & 127) * 2;
        *(half2_t*)(sm + VT_OFF + jh * 2048 + 1792 + w2) =
            (half2_t){(_Float16)0.f, (_Float16)0.f};
    }

    // epilogue: scatter accs -> fragment-packed LDS (XS dead)
    #pragma unroll
    for (int i = 0; i < 4; ++i) {
        if (i >= NI) break;
        #pragma unroll
        for (int r = 0; r < 4; ++r) {
            int row = mh * 64 + i * 16 + lg * 4 + r;   // time index 0..111
            if (!isK) {
                {   // q tile t0
                    int h = t0 * 16 + l15;
                    int off = (row >> 4) * 1024 + (h >> 5) * 512
                            + (((h >> 3) & 3) * 16 + (row & 15)) * 8 + (h & 7);
                    float v0 = acc0[i][r];
                    _Float16 hh = (_Float16)v0;
                    sm[QH_OFF + off] = hh;
                    sm[QL_OFF + off] = (_Float16)(v0 - (float)hh);
                }
                {   // q tile t1
                    int h = t1 * 16 + l15;
                    int off = (row >> 4) * 1024 + (h >> 5) * 512
                            + (((h >> 3) & 3) * 16 + (row & 15)) * 8 + (h & 7);
                    float v0 = acc1[i][r];
                    _Float16 hh = (_Float16)v0;
                    sm[QH_OFF + off] = hh;
                    sm[QL_OFF + off] = (_Float16)(v0 - (float)hh);
                }
                {   // v tile t2
                    int h = (t2 - 8) * 16 + l15;
                    int off = (h >> 4) * 2048 + (row >> 5) * 512
                            + (((row >> 3) & 3) * 16 + (h & 15)) * 8 + (row & 7);
                    sm[VT_OFF + off] = (_Float16)acc2[i][r];
                }
                {   // v tile t3
                    int h = (t3 - 8) * 16 + l15;
                    int off = (h >> 4) * 2048 + (row >> 5) * 512
                            + (((row >> 3) & 3) * 16 + (h & 15)) * 8 + (row & 7);
                    sm[VT_OFF + off] = (_Float16)acc3[i][r];
                }
            } else {
                {   // k tile t0
                    int h = (t0 - 4) * 16 + l15;
                    int off = (row >> 4) * 1024 + (h >> 5) * 512
                            + (((h >> 3) & 3) * 16 + (row & 15)) * 8 + (h & 7);
                    float v0 = acc0[i][r];
                    _Float16 hh = (_Float16)v0;
                    sm[KH_OFF + off] = hh;
                    sm[KL_OFF + off] = (_Float16)(v0 - (float)hh);
                }
                {   // k tile t1
                    int h = (t1 - 4) * 16 + l15;
                    int off = (row >> 4) * 1024 + (h >> 5) * 512
                            + (((h >> 3) & 3) * 16 + (row & 15)) * 8 + (h & 7);
                    float v0 = acc1[i][r];
                    _Float16 hh = (_Float16)v0;
                    sm[KH_OFF + off] = hh;
                    sm[KL_OFF + off] = (_Float16)(v0 - (float)hh);
                }
            }
        }
    }
    __syncthreads();

    // ================= phase 2: scores (split fp16), softmax (waves 0..6) ============
    f32x4 sacc[7];
    float rsum[4] = {0.f, 0.f, 0.f, 0.f};

    if (wid < 7) {
        #pragma unroll
        for (int j = 0; j < 7; ++j) sacc[j] = (f32x4){0.f,0.f,0.f,0.f};
        #pragma unroll
        for (int kk = 0; kk < 2; ++kk) {
            half8 qh = *(const half8*)(sm + QH_OFF + wid * 1024 + kk * 512 + lane * 8);
            half8 ql = *(const half8*)(sm + QL_OFF + wid * 1024 + kk * 512 + lane * 8);
            #pragma unroll
            for (int j = 0; j < 7; ++j) {
                half8 kh = *(const half8*)(sm + KH_OFF + j * 1024 + kk * 512 + lane * 8);
                half8 kl = *(const half8*)(sm + KL_OFF + j * 1024 + kk * 512 + lane * 8);
                sacc[j] = __builtin_amdgcn_mfma_f32_16x16x32_f16(qh, kh, sacc[j], 0, 0, 0);
                sacc[j] = __builtin_amdgcn_mfma_f32_16x16x32_f16(ql, kh, sacc[j], 0, 0, 0);
                sacc[j] = __builtin_amdgcn_mfma_f32_16x16x32_f16(qh, kl, sacc[j], 0, 0, 0);
            }
        }
        float rmax[4] = {-1e30f, -1e30f, -1e30f, -1e30f};
        #pragma unroll
        for (int j = 0; j < 7; ++j) {
            int key = j * 16 + l15;
            #pragma unroll
            for (int r = 0; r < 4; ++r) {
                int row = wid * 16 + lg * 4 + r;
                // faithful bug: multiply by sqrt(64)=8; causal + key<100 mask
                float s = (key <= row && key < T_CTX) ? sacc[j][r] * 8.0f : -1e30f;
                sacc[j][r] = s;
                rmax[r] = fmaxf(rmax[r], s);
            }
        }
        #pragma unroll
        for (int r = 0; r < 4; ++r) {
            #pragma unroll
            for (int d = 1; d < 16; d <<= 1)
                rmax[r] = fmaxf(rmax[r], __shfl_xor(rmax[r], d, 64));
            rsum[r] = rmax[r];   // stash rmax through the barrier (rsum reused below)
        }
    }
    __syncthreads();   // all q/k reads done before PS overlays that region

    if (wid < 7) {
        float rmax[4];
        #pragma unroll
        for (int r = 0; r < 4; ++r) { rmax[r] = rsum[r]; rsum[r] = 0.f; }
        #pragma unroll
        for (int j = 0; j < 7; ++j) {
            int key = j * 16 + l15;
            #pragma unroll
            for (int r = 0; r < 4; ++r) {
                float p = __expf(sacc[j][r] - rmax[r]);   // masked -> 0
                rsum[r] += p;
                int a = lg * 4 + r;
                int off = wid * 2048 + (key >> 5) * 512
                        + (((key >> 3) & 3) * 16 + a) * 8 + (key & 7);
                sm[PS_OFF + off] = (_Float16)p;
            }
        }
        #pragma unroll
        for (int r = 0; r < 4; ++r) {                   // zero pad keys 112..127
            int key = 112 + l15;
            int a = lg * 4 + r;
            int off = wid * 2048 + (key >> 5) * 512
                    + (((key >> 3) & 3) * 16 + a) * 8 + (key & 7);
            sm[PS_OFF + off] = (_Float16)0.f;
            #pragma unroll
            for (int d = 1; d < 16; d <<= 1)
                rsum[r] += __shfl_xor(rsum[r], d, 64);
        }
    }
    __syncthreads();

    // ================= phase 3: out = (P @ V) / rowsum (waves 0..6) ===================
    if (wid < 7) {
        f32x4 oacc[4];
        #pragma unroll
        for (int j = 0; j < 4; ++j) oacc[j] = (f32x4){0.f,0.f,0.f,0.f};
        #pragma unroll
        for (int kk = 0; kk < 4; ++kk) {
            half8 pa = *(const half8*)(sm + PS_OFF + wid * 2048 + kk * 512 + lane * 8);
            #pragma unroll
            for (int jh = 0; jh < 4; ++jh) {
                half8 vb = *(const half8*)(sm + VT_OFF + jh * 2048 + kk * 512 + lane * 8);
                oacc[jh] = __builtin_amdgcn_mfma_f32_16x16x32_f16(pa, vb, oacc[jh], 0, 0, 0);
            }
        }
        float rinv[4];
        #pragma unroll
        for (int r = 0; r < 4; ++r) rinv[r] = 1.0f / rsum[r];
        #pragma unroll
        for (int jh = 0; jh < 4; ++jh) {
            #pragma unroll
            for (int r = 0; r < 4; ++r) {
                int t = wid * 16 + lg * 4 + r;
                if (t < T_CTX)
                    out[((size_t)b * T_CTX + t) * H_DIM + jh * 16 + l15] = oacc[jh][r] * rinv[r];
            }
        }
    }
}

extern "C" void kernel_launch(void* const* d_in, const int* in_sizes, int n_in,
                              void* d_out, int out_size, void* d_ws, size_t ws_size,
                              hipStream_t stream) {
    const float* x  = (const float*)d_in[0];
    const float* Wq = (const float*)d_in[1];
    const float* Wk = (const float*)d_in[2];
    const float* Wv = (const float*)d_in[3];

    _Float16* wf_hi = (_Float16*)d_ws;                 // 12*12*64*8 halfs = 147456 B
    _Float16* wf_lo = wf_hi + (size_t)9216 * 8;        // total ws use: 294912 B

    prep_w_kernel<<<36, 256, 0, stream>>>(Wq, Wk, Wv, wf_hi, wf_lo);

    (void)hipFuncSetAttribute((const void*)head_kernel,
                              hipFuncAttributeMaxDynamicSharedMemorySize, SMEM_BYTES);
    head_kernel<<<1024, 512, SMEM_BYTES, stream>>>(x, wf_hi, wf_lo, (float*)d_out);
}

// Round 7
// 63.817 us; speedup vs baseline: 1.6405x; 1.1780x over previous
//
#include <hip/hip_runtime.h>
#include <hip/hip_fp16.h>

#define T_CTX 100
#define C_DIM 384
#define H_DIM 64

typedef _Float16 half8   __attribute__((ext_vector_type(8)));
typedef _Float16 half4_t __attribute__((ext_vector_type(4)));
typedef _Float16 half2_t __attribute__((ext_vector_type(2)));
typedef float    f32x4   __attribute__((ext_vector_type(4)));

// ---- LDS layout, units = halfs (2B) ----
// Persistent (phase2/3), 7 row-tiles (rows 0..111):
//   QH [7][2 kk][64][8] @ 0      (7168 halfs)
//   QL                  @ 7168   (7168)
//   KH [7][2 kk][64][8] @ 14336  (7168)
//   KL                  @ 21504  (7168)
//   VT [4 jh][4 kk][64][8] @ 28672 (8192)
//   total 36864 halfs = 73728 B -> 2 blocks/CU
// Overlays @0 (dead regions at time of use):
//   XS (R1-proven): 2 buf x {hi [128][40], lo @ +5120} = 20480 halfs (40960 B)
//   PS: [7 wid][4 kk][64][8] halfs (14336)
#define QH_OFF 0
#define QL_OFF 7168
#define KH_OFF 14336
#define KL_OFF 21504
#define VT_OFF 28672
#define PS_OFF 0
#define SMEM_BYTES 73728

__global__ void prep_w_kernel(const float* __restrict__ Wq,
                              const float* __restrict__ Wk,
                              const float* __restrict__ Wv,
                              _Float16* __restrict__ wf_hi,
                              _Float16* __restrict__ wf_lo) {
    int idx = blockIdx.x * 256 + threadIdx.x;   // over 12*12*64 = 9216 frag-lanes
    if (idx >= 9216) return;
    int lane  = idx & 63;
    int chunk = (idx >> 6) % 12;
    int jt    = idx / (64 * 12);
    int col   = jt * 16 + (lane & 15);          // global N col 0..191 (q|k|v)
    const float* W = (col < 64) ? Wq : ((col < 128) ? Wk : Wv);
    int h = col & 63;
    int cbase = chunk * 32 + (lane >> 4) * 8;   // K index base
    #pragma unroll
    for (int e = 0; e < 8; ++e) {
        float f = W[(size_t)(cbase + e) * H_DIM + h];
        _Float16 hi = (_Float16)f;
        _Float16 lo = (_Float16)(f - (float)hi);
        size_t o = (size_t)idx * 8 + e;
        wf_hi[o] = hi;
        wf_lo[o] = lo;
    }
}

// 4 fp32 -> fp16 hi/lo half4 planes (producer-side, 1x per element)
__device__ inline void cvt4(f32x4 v, half4_t& hh, half4_t& ll) {
    #pragma unroll
    for (int u = 0; u < 4; ++u) {
        _Float16 h = (_Float16)v[u];
        hh[u] = h;
        ll[u] = (_Float16)(v[u] - (float)h);
    }
}

__global__ __launch_bounds__(512, 4)
void head_kernel(const float* __restrict__ x,
                 const _Float16* __restrict__ wf_hi,
                 const _Float16* __restrict__ wf_lo,
                 float* __restrict__ out) {
    extern __shared__ _Float16 sm[];

    const int b    = blockIdx.x;
    const int tid  = threadIdx.x;
    const int lane = tid & 63;
    const int wid  = tid >> 6;      // 8 waves
    const int l15  = lane & 15;
    const int lg   = lane >> 4;     // 0..3
    const int mh   = wid >> 2;      // row half
    const int nw   = wid & 3;
    const int NI   = (mh == 0) ? 4 : 3;   // mh=1 skips rows 112..127
    const bool isK = (nw >= 2);

    // wave -> B tiles (wf layout: tiles 0-3 q, 4-7 k, 8-11 v; tile stride 12*512=6144)
    int t0, t1;
    const _Float16 *pw0, *pw1, *pw2, *pw3;
    if (!isK) {
        t0 = nw * 2; t1 = t0 + 1;
        pw0 = wf_hi + (size_t)t0 * 6144;
        pw1 = wf_hi + (size_t)t1 * 6144;
        pw2 = wf_hi + (size_t)(8 + nw * 2) * 6144;      // v hi
        pw3 = wf_hi + (size_t)(9 + nw * 2) * 6144;
    } else {
        t0 = 4 + (nw - 2) * 2; t1 = t0 + 1;
        pw0 = wf_hi + (size_t)t0 * 6144;
        pw1 = wf_hi + (size_t)t1 * 6144;
        pw2 = wf_lo + (size_t)t0 * 6144;                // k lo
        pw3 = wf_lo + (size_t)t1 * 6144;
    }

    const float* xb = x + (size_t)b * T_CTX * C_DIM;

    // ================= phase 1: q,k,v = x @ W (R1-proven fp16 hi/lo staging) =========
    f32x4 acc0[4], acc1[4], acc2[4], acc3[4];
    #pragma unroll
    for (int i = 0; i < 4; ++i) {
        acc0[i] = (f32x4){0.f,0.f,0.f,0.f};
        acc1[i] = (f32x4){0.f,0.f,0.f,0.f};
        acc2[i] = (f32x4){0.f,0.f,0.f,0.f};
        acc3[i] = (f32x4){0.f,0.f,0.f,0.f};
    }

    // prologue: stage chunk 0 -> buf 0
    #pragma unroll
    for (int s = 0; s < 2; ++s) {
        int f4  = tid + s * 512;
        int row = f4 >> 3;
        int c4  = f4 & 7;
        f32x4 v = (f32x4){0.f, 0.f, 0.f, 0.f};
        if (row < T_CTX) v = *(const f32x4*)(xb + (size_t)row * C_DIM + c4 * 4);
        half4_t hh, ll;
        cvt4(v, hh, ll);
        int o = row * 40 + c4 * 4;
        *(half4_t*)(sm + o)        = hh;
        *(half4_t*)(sm + 5120 + o) = ll;
    }
    // preload W chunk 0 into registers
    half8 W0 = *(const half8*)(pw0 + lane * 8);
    half8 W1 = *(const half8*)(pw1 + lane * 8);
    half8 W2 = *(const half8*)(pw2 + lane * 8);
    half8 W3 = *(const half8*)(pw3 + lane * 8);
    __syncthreads();

    #pragma unroll 1
    for (int kc = 0; kc < 12; ++kc) {
        const int nk = kc + 1;
        f32x4 ld[2];
        half8 N0 = W0, N1 = W1, N2 = W2, N3 = W3;
        if (nk < 12) {   // issue next-chunk global loads + W prefetch early
            #pragma unroll
            for (int s = 0; s < 2; ++s) {
                int f4  = tid + s * 512;
                int row = f4 >> 3;
                int c4  = f4 & 7;
                ld[s] = (f32x4){0.f, 0.f, 0.f, 0.f};
                if (row < T_CTX)
                    ld[s] = *(const f32x4*)(xb + (size_t)row * C_DIM + nk * 32 + c4 * 4);
            }
            const int wo = nk * 512 + lane * 8;
            N0 = *(const half8*)(pw0 + wo);
            N1 = *(const half8*)(pw1 + wo);
            N2 = *(const half8*)(pw2 + wo);
            N3 = *(const half8*)(pw3 + wo);
        }

        const _Float16* xh = sm + (kc & 1) * 10240;
        const _Float16* xl = xh + 5120;
        #pragma unroll
        for (int i = 0; i < 4; ++i) {
            if (i >= NI) break;
            int row = mh * 64 + i * 16 + l15;
            int o = row * 40 + lg * 8;
            half8 ah = *(const half8*)(xh + o);
            half8 al = *(const half8*)(xl + o);
            // q (2-prod) / k (3-prod) on acc0/acc1; v (1-prod) on acc2/acc3
            acc0[i] = __builtin_amdgcn_mfma_f32_16x16x32_f16(ah, W0, acc0[i], 0, 0, 0);
            acc0[i] = __builtin_amdgcn_mfma_f32_16x16x32_f16(al, W0, acc0[i], 0, 0, 0);
            acc1[i] = __builtin_amdgcn_mfma_f32_16x16x32_f16(ah, W1, acc1[i], 0, 0, 0);
            acc1[i] = __builtin_amdgcn_mfma_f32_16x16x32_f16(al, W1, acc1[i], 0, 0, 0);
            if (!isK) {
                acc2[i] = __builtin_amdgcn_mfma_f32_16x16x32_f16(ah, W2, acc2[i], 0, 0, 0);
                acc3[i] = __builtin_amdgcn_mfma_f32_16x16x32_f16(ah, W3, acc3[i], 0, 0, 0);
            } else {
                acc0[i] = __builtin_amdgcn_mfma_f32_16x16x32_f16(ah, W2, acc0[i], 0, 0, 0);
                acc1[i] = __builtin_amdgcn_mfma_f32_16x16x32_f16(ah, W3, acc1[i], 0, 0, 0);
            }
        }

        if (nk < 12) {   // producer-side cvt + write next chunk into other buffer
            const int nb = (nk & 1) * 10240;
            #pragma unroll
            for (int s = 0; s < 2; ++s) {
                int f4  = tid + s * 512;
                int row = f4 >> 3;
                int c4  = f4 & 7;
                half4_t hh, ll;
                cvt4(ld[s], hh, ll);
                int o = row * 40 + c4 * 4;
                *(half4_t*)(sm + nb + o)        = hh;
                *(half4_t*)(sm + nb + 5120 + o) = ll;
            }
        }
        __syncthreads();
        W0 = N0; W1 = N1; W2 = N2; W3 = N3;
    }

    // VT zero-fill rows 112..127
    {
        int jh = tid >> 7;
        int w2 = (tid & 127) * 2;
        *(half2_t*)(sm + VT_OFF + jh * 2048 + 1792 + w2) =
            (half2_t){(_Float16)0.f, (_Float16)0.f};
    }

    // epilogue: scatter accs -> fragment-packed LDS (XS dead)
    #pragma unroll
    for (int i = 0; i < 4; ++i) {
        if (i >= NI) break;
        #pragma unroll
        for (int r = 0; r < 4; ++r) {
            int row = mh * 64 + i * 16 + lg * 4 + r;   // time index 0..111
            if (!isK) {
                {   // q tile t0
                    int h = t0 * 16 + l15;
                    int off = (row >> 4) * 1024 + (h >> 5) * 512
                            + (((h >> 3) & 3) * 16 + (row & 15)) * 8 + (h & 7);
                    float v0 = acc0[i][r];
                    _Float16 hh = (_Float16)v0;
                    sm[QH_OFF + off] = hh;
                    sm[QL_OFF + off] = (_Float16)(v0 - (float)hh);
                }
                {   // q tile t1
                    int h = t1 * 16 + l15;
                    int off = (row >> 4) * 1024 + (h >> 5) * 512
                            + (((h >> 3) & 3) * 16 + (row & 15)) * 8 + (h & 7);
                    float v0 = acc1[i][r];
                    _Float16 hh = (_Float16)v0;
                    sm[QH_OFF + off] = hh;
                    sm[QL_OFF + off] = (_Float16)(v0 - (float)hh);
                }
                {   // v tile nw*2
                    int h = nw * 32 + l15;
                    int off = (h >> 4) * 2048 + (row >> 5) * 512
                            + (((row >> 3) & 3) * 16 + (h & 15)) * 8 + (row & 7);
                    sm[VT_OFF + off] = (_Float16)acc2[i][r];
                }
                {   // v tile nw*2+1
                    int h = nw * 32 + 16 + l15;
                    int off = (h >> 4) * 2048 + (row >> 5) * 512
                            + (((row >> 3) & 3) * 16 + (h & 15)) * 8 + (row & 7);
                    sm[VT_OFF + off] = (_Float16)acc3[i][r];
                }
            } else {
                {   // k tile t0
                    int h = (t0 - 4) * 16 + l15;
                    int off = (row >> 4) * 1024 + (h >> 5) * 512
                            + (((h >> 3) & 3) * 16 + (row & 15)) * 8 + (h & 7);
                    float v0 = acc0[i][r];
                    _Float16 hh = (_Float16)v0;
                    sm[KH_OFF + off] = hh;
                    sm[KL_OFF + off] = (_Float16)(v0 - (float)hh);
                }
                {   // k tile t1
                    int h = (t1 - 4) * 16 + l15;
                    int off = (row >> 4) * 1024 + (h >> 5) * 512
                            + (((h >> 3) & 3) * 16 + (row & 15)) * 8 + (h & 7);
                    float v0 = acc1[i][r];
                    _Float16 hh = (_Float16)v0;
                    sm[KH_OFF + off] = hh;
                    sm[KL_OFF + off] = (_Float16)(v0 - (float)hh);
                }
            }
        }
    }
    __syncthreads();

    // ================= phase 2: scores (split fp16), softmax (waves 0..6) ============
    f32x4 sacc[7];
    float rsum[4] = {0.f, 0.f, 0.f, 0.f};

    if (wid < 7) {
        #pragma unroll
        for (int j = 0; j < 7; ++j) sacc[j] = (f32x4){0.f,0.f,0.f,0.f};
        #pragma unroll
        for (int kk = 0; kk < 2; ++kk) {
            half8 qh = *(const half8*)(sm + QH_OFF + wid * 1024 + kk * 512 + lane * 8);
            half8 ql = *(const half8*)(sm + QL_OFF + wid * 1024 + kk * 512 + lane * 8);
            #pragma unroll
            for (int j = 0; j < 7; ++j) {
                half8 kh = *(const half8*)(sm + KH_OFF + j * 1024 + kk * 512 + lane * 8);
                half8 kl = *(const half8*)(sm + KL_OFF + j * 1024 + kk * 512 + lane * 8);
                sacc[j] = __builtin_amdgcn_mfma_f32_16x16x32_f16(qh, kh, sacc[j], 0, 0, 0);
                sacc[j] = __builtin_amdgcn_mfma_f32_16x16x32_f16(ql, kh, sacc[j], 0, 0, 0);
                sacc[j] = __builtin_amdgcn_mfma_f32_16x16x32_f16(qh, kl, sacc[j], 0, 0, 0);
            }
        }
        float rmax[4] = {-1e30f, -1e30f, -1e30f, -1e30f};
        #pragma unroll
        for (int j = 0; j < 7; ++j) {
            int key = j * 16 + l15;
            #pragma unroll
            for (int r = 0; r < 4; ++r) {
                int row = wid * 16 + lg * 4 + r;
                // faithful bug: multiply by sqrt(64)=8; causal + key<100 mask
                float s = (key <= row && key < T_CTX) ? sacc[j][r] * 8.0f : -1e30f;
                sacc[j][r] = s;
                rmax[r] = fmaxf(rmax[r], s);
            }
        }
        #pragma unroll
        for (int r = 0; r < 4; ++r) {
            #pragma unroll
            for (int d = 1; d < 16; d <<= 1)
                rmax[r] = fmaxf(rmax[r], __shfl_xor(rmax[r], d, 64));
            rsum[r] = rmax[r];   // stash rmax across the barrier
        }
    }
    __syncthreads();   // all q/k reads done before PS overlays that region

    if (wid < 7) {
        float rmax[4];
        #pragma unroll
        for (int r = 0; r < 4; ++r) { rmax[r] = rsum[r]; rsum[r] = 0.f; }
        #pragma unroll
        for (int j = 0; j < 7; ++j) {
            int key = j * 16 + l15;
            #pragma unroll
            for (int r = 0; r < 4; ++r) {
                float p = __expf(sacc[j][r] - rmax[r]);   // masked -> 0
                rsum[r] += p;
                int a = lg * 4 + r;
                int off = wid * 2048 + (key >> 5) * 512
                        + (((key >> 3) & 3) * 16 + a) * 8 + (key & 7);
                sm[PS_OFF + off] = (_Float16)p;
            }
        }
        #pragma unroll
        for (int r = 0; r < 4; ++r) {                   // zero pad keys 112..127
            int key = 112 + l15;
            int a = lg * 4 + r;
            int off = wid * 2048 + (key >> 5) * 512
                    + (((key >> 3) & 3) * 16 + a) * 8 + (key & 7);
            sm[PS_OFF + off] = (_Float16)0.f;
            #pragma unroll
            for (int d = 1; d < 16; d <<= 1)
                rsum[r] += __shfl_xor(rsum[r], d, 64);
        }
    }
    __syncthreads();

    // ================= phase 3: out = (P @ V) / rowsum (waves 0..6) ===================
    if (wid < 7) {
        f32x4 oacc[4];
        #pragma unroll
        for (int j = 0; j < 4; ++j) oacc[j] = (f32x4){0.f,0.f,0.f,0.f};
        #pragma unroll
        for (int kk = 0; kk < 4; ++kk) {
            half8 pa = *(const half8*)(sm + PS_OFF + wid * 2048 + kk * 512 + lane * 8);
            #pragma unroll
            for (int jh = 0; jh < 4; ++jh) {
                half8 vb = *(const half8*)(sm + VT_OFF + jh * 2048 + kk * 512 + lane * 8);
                oacc[jh] = __builtin_amdgcn_mfma_f32_16x16x32_f16(pa, vb, oacc[jh], 0, 0, 0);
            }
        }
        float rinv[4];
        #pragma unroll
        for (int r = 0; r < 4; ++r) rinv[r] = 1.0f / rsum[r];
        #pragma unroll
        for (int jh = 0; jh < 4; ++jh) {
            #pragma unroll
            for (int r = 0; r < 4; ++r) {
                int t = wid * 16 + lg * 4 + r;
                if (t < T_CTX)
                    out[((size_t)b * T_CTX + t) * H_DIM + jh * 16 + l15] = oacc[jh][r] * rinv[r];
            }
        }
    }
}

extern "C" void kernel_launch(void* const* d_in, const int* in_sizes, int n_in,
                              void* d_out, int out_size, void* d_ws, size_t ws_size,
                              hipStream_t stream) {
    const float* x  = (const float*)d_in[0];
    const float* Wq = (const float*)d_in[1];
    const float* Wk = (const float*)d_in[2];
    const float* Wv = (const float*)d_in[3];

    _Float16* wf_hi = (_Float16*)d_ws;                 // 12*12*64*8 halfs = 147456 B
    _Float16* wf_lo = wf_hi + (size_t)9216 * 8;        // total ws use: 294912 B

    prep_w_kernel<<<36, 256, 0, stream>>>(Wq, Wk, Wv, wf_hi, wf_lo);

    (void)hipFuncSetAttribute((const void*)head_kernel,
                              hipFuncAttributeMaxDynamicSharedMemorySize, SMEM_BYTES);
    head_kernel<<<1024, 512, SMEM_BYTES, stream>>>(x, wf_hi, wf_lo, (float*)d_out);
}